// Round 7
// baseline (647.125 us; speedup 1.0000x reference)
//
#include <hip/hip_runtime.h>
#include <math.h>

typedef float f4  __attribute__((ext_vector_type(4)));
typedef short s8v __attribute__((ext_vector_type(8)));   // 8 bf16 (4 VGPRs)
typedef unsigned short u16;
typedef u16 us4 __attribute__((ext_vector_type(4)));

#define PLANE (4096*4096)

// ---- output offsets (floats), concatenated return order ----
#define OUT_COL 0
#define OUT_ROW 262144
#define OUT_OBJ 524288
#define OUT_CV  524352
#define OUT_VC  34078784
#define OUT_VO  67633216
#define OUT_CO  67641408

// ---- workspace offsets (floats) ----
#define WS_VO_P  0         // [16][64] v->o attention per-block partials
#define WS_CO_P  1024      // [16][64] c->o attention per-block partials
#define WS_OBJ1  2048      // [64]  obj after v->o update
#define WS_RDCV  2112      // [4096] row_hidden . w_cv_row
#define WS_CDCV  6208      // [4096] col_hidden . w_cv_col
#define WS_RDVC  10304     // [4096] row_next . w_vc_row
#define WS_CDVC  14400     // [4096] col_hidden . w_vc_col
#define WS_GPART 18496     // [8][4096*64] f32 K-split partials (8 MB)
#define WS_SC    2115648   // [4096*4096] bf16 score plane (32 MB)
#define WS_BT1   10504256  // [64][4096] bf16 col_hidden^T
#define WS_BT2   10635328  // [64][4096] bf16 row_next^T

__device__ __forceinline__ float sigf(float x) {
    return 1.0f / (1.0f + __expf(-x));
}
__device__ __forceinline__ u16 f2bf(float x) {       // RNE float->bf16
    unsigned u = __float_as_uint(x);
    return (u16)((u + 0x7FFFu + ((u >> 16) & 1u)) >> 16);
}

// ---------------------------------------------------------------------------
// 64x64 fp32 -> bf16 transpose tile: BT[h][k0+c] = X[k0+c][h].
__device__ __forceinline__ void transpose_tile(int k0, int t,
    const float* __restrict__ X, u16* __restrict__ BT, float* lds /*64*72*/)
{
    #pragma unroll
    for (int it = 0; it < 4; ++it) {
        const int idx = it * 256 + t;          // 0..1023 f4 units
        const int r = idx >> 4, c4 = (idx & 15) * 4;
        f4 v = *(const f4*)(X + (size_t)(k0 + r) * 64 + c4);
        *(f4*)(lds + r * 72 + c4) = v;
    }
    __syncthreads();
    #pragma unroll
    for (int it = 0; it < 4; ++it) {
        const int idx = it * 256 + t;          // 0..1023
        const int h = idx >> 4, q = (idx & 15) * 4;
        us4 o;
        o.x = f2bf(lds[(q + 0) * 72 + h]);
        o.y = f2bf(lds[(q + 1) * 72 + h]);
        o.z = f2bf(lds[(q + 2) * 72 + h]);
        o.w = f2bf(lds[(q + 3) * 72 + h]);
        *(us4*)(BT + (size_t)h * 4096 + k0 + q) = o;
    }
}

// ---------------------------------------------------------------------------
// Attention body: per-block partial, no global atomics.
__device__ __forceinline__ void attn_body(
    int blk, int t, const float* __restrict__ X, const float* __restrict__ supp,
    const float* __restrict__ obj, const float* __restrict__ wat,
    const float* __restrict__ bat, float* __restrict__ accP,
    float* sA, float* sAcc)
{
    const int i = blk * 256 + t;
    float od = 0.f;
    for (int h = 0; h < 64; ++h) od += obj[h] * wat[66 + h];
    float x = bat[0] + od + supp[i*2] * wat[64] + supp[i*2+1] * wat[65];
    const f4* Xr = (const f4*)(X + i*64);
    f4 xd = 0.f;
    #pragma unroll
    for (int q = 0; q < 16; ++q) xd += Xr[q] * ((const f4*)wat)[q];
    x += xd.x + xd.y + xd.z + xd.w;
    sA[t] = sigf(x);
    if (t < 64) sAcc[t] = 0.f;
    __syncthreads();
    const int w = t >> 6, h = t & 63;
    const int base = blk * 256 + w * 64;
    float partial = 0.f;
    for (int j = 0; j < 64; ++j)
        partial += sA[w*64 + j] * X[(base + j)*64 + h];
    atomicAdd(&sAcc[h], partial);
    __syncthreads();
    if (t < 64) accP[blk*64 + t] = sAcc[t];
}

// ---------------------------------------------------------------------------
// Front: 3072 dot blocks + 16 small-copy + 16 v->o attn + 64 BT1-transpose.
__global__ __launch_bounds__(256) void k_front(
    const float* __restrict__ col_hidden, const float* __restrict__ row_hidden,
    const float* __restrict__ w_cv_col, const float* __restrict__ w_vc_col,
    const float* __restrict__ w_cv_row,
    float* __restrict__ cdcv, float* __restrict__ cdvc, float* __restrict__ rdcv,
    const float* __restrict__ vo_supp, const float* __restrict__ co_supp,
    float* __restrict__ out_vo, float* __restrict__ out_co,
    const float* __restrict__ obj_hidden, const float* __restrict__ w_attn_vo,
    const float* __restrict__ b_attn_vo, float* __restrict__ voP,
    u16* __restrict__ BT1)
{
    __shared__ float sA[256];
    __shared__ float sAcc[64];
    __shared__ float tr[64*72];
    const int t = threadIdx.x;
    if (blockIdx.x < 3072) {
        const int gw = blockIdx.x * 4 + (t >> 6);
        const int lane = t & 63;
        const int which = gw >> 12;
        const int row = gw & 4095;
        const float* x; const float* w; float* dst;
        if (which == 0)      { x = col_hidden; w = w_cv_col; dst = cdcv; }
        else if (which == 1) { x = col_hidden; w = w_vc_col; dst = cdvc; }
        else                 { x = row_hidden; w = w_cv_row; dst = rdcv; }
        float v = x[row * 64 + lane] * w[lane];
        #pragma unroll
        for (int off = 32; off; off >>= 1) v += __shfl_down(v, off, 64);
        if (lane == 0) dst[row] = v;
        return;
    }
    if (blockIdx.x < 3088) {
        const int idx = (blockIdx.x - 3072) * 256 + t;
        if (idx < 2048) ((f4*)out_vo)[idx] = ((const f4*)vo_supp)[idx];
        else            ((f4*)out_co)[idx - 2048] = ((const f4*)co_supp)[idx - 2048];
        return;
    }
    if (blockIdx.x < 3104) {
        attn_body(blockIdx.x - 3088, t, col_hidden, vo_supp, obj_hidden,
                  w_attn_vo, b_attn_vo, voP, sA, sAcc);
        return;
    }
    transpose_tile((blockIdx.x - 3104) * 64, t, col_hidden, BT1, tr);
}

// ---------------------------------------------------------------------------
// c->o attention (16 blocks) + BT2 transpose of row_next (64 blocks).
__global__ __launch_bounds__(256) void k_attn(
    const float* __restrict__ X, const float* __restrict__ supp,
    const float* __restrict__ obj, const float* __restrict__ wat,
    const float* __restrict__ bat, float* __restrict__ accP,
    u16* __restrict__ BT2)
{
    __shared__ float sA[256];
    __shared__ float sAcc[64];
    __shared__ float tr[64*72];
    if (blockIdx.x < 16) {
        attn_body(blockIdx.x, threadIdx.x, X, supp, obj, wat, bat, accP, sA, sAcc);
        return;
    }
    transpose_tile((blockIdx.x - 16) * 64, threadIdx.x, X, BT2, tr);
}

// ---------------------------------------------------------------------------
// Pure pass-through copy of BOTH supp tensors — EXACT m13 copy shape:
// plain f4 load + f4 store, 2 streams, no LDS, no barriers, no nt.
// grid = 16384 blocks: [0,8192) cv tensor, [8192,16384) vc tensor.
// Per tensor: 2*PLANE floats = 8.39M f4; per block 1024 contiguous f4.
// DIAGNOSTIC: if this shows in rocprof top-5 (>=163us, <3.1 TB/s), big-buffer
// R/W streams are capped by the platform, not by kernel structure.
__global__ __launch_bounds__(256) void k_copy(
    const float* __restrict__ a, const float* __restrict__ b,
    float* __restrict__ da, float* __restrict__ db)
{
    const int t = threadIdx.x;
    const f4* src; f4* dst; size_t off;
    if (blockIdx.x < 8192) { src = (const f4*)a; dst = (f4*)da; off = (size_t)blockIdx.x * 1024; }
    else                   { src = (const f4*)b; dst = (f4*)db; off = (size_t)(blockIdx.x - 8192) * 1024; }
    #pragma unroll
    for (int it = 0; it < 4; ++it) {
        const size_t i = off + t + it * 256;
        dst[i] = src[i];
    }
}

// ---------------------------------------------------------------------------
// Score pass: read the two supp planes, write masked bf16 sigmoid scores.
//   score(i,j) = [s0!=0] * sig(perrow[i] + percol[j] + w0*s0 + w1*s1 + b)
// One 4096-float row per block (row index uniform -> scalar perrow load).
__global__ __launch_bounds__(256) void k_score(
    const float* __restrict__ supp0, const float* __restrict__ supp1,
    const float* __restrict__ perrow, const float* __restrict__ percol,
    const float* __restrict__ wsup, const float* __restrict__ bias,
    u16* __restrict__ score)
{
    const float w0 = wsup[0], w1 = wsup[1], bv = bias[0];
    const float rd = perrow[blockIdx.x];
    const size_t base = (size_t)blockIdx.x * 1024 + threadIdx.x;
    #pragma unroll
    for (int it = 0; it < 4; ++it) {
        const size_t idx = base + it * 256;
        const int j0 = (int)(idx & 1023) * 4;
        f4 a0 = ((const f4*)supp0)[idx];
        f4 a1 = ((const f4*)supp1)[idx];
        f4 cd = *(const f4*)(percol + j0);
        f4 lg = rd + cd + w0 * a0 + w1 * a1 + bv;
        us4 o;
        o.x = (a0.x != 0.f) ? f2bf(sigf(lg.x)) : (u16)0;
        o.y = (a0.y != 0.f) ? f2bf(sigf(lg.y)) : (u16)0;
        o.z = (a0.z != 0.f) ? f2bf(sigf(lg.z)) : (u16)0;
        o.w = (a0.w != 0.f) ? f2bf(sigf(lg.w)) : (u16)0;
        ((us4*)score)[idx] = o;
    }
}

// ---------------------------------------------------------------------------
// MFMA GEMM: part[ks] = scores[4096x4096 bf16] @ BT^T[4096x64 bf16] (K-split 8).
// Layouts verified on-device (R6 absmax=32 = pure bf16 noise).
__global__ __launch_bounds__(256, 4) void k_gemm(
    const u16* __restrict__ sc, const u16* __restrict__ BT,
    float* __restrict__ part,
    const float* __restrict__ objL, const float* __restrict__ objRp,
    const float* __restrict__ Wobj, float* __restrict__ objDst)
{
    __shared__ float rsum[64];
    const int t = threadIdx.x;
    if (blockIdx.x == 512) {
        if (t < 64) {
            float r = 0.f;
            for (int b = 0; b < 16; ++b) r += objRp[b*64 + t];
            rsum[t] = r;
        }
        __syncthreads();
        if (t < 64) {
            float acc = 0.f;
            for (int k = 0; k < 64; ++k) acc += objL[k] * Wobj[k*64 + t];
            for (int k = 0; k < 64; ++k) acc += rsum[k] * Wobj[(64+k)*64 + t];
            objDst[t] = fmaxf(acc, 0.f);
        }
        return;
    }
    const int mblk = blockIdx.x >> 3;
    const int ks   = blockIdx.x & 7;
    const int wv   = t >> 6, lane = t & 63;
    const int i0   = mblk * 64 + wv * 16;
    const int m    = lane & 15, quad = lane >> 4;
    const int k0   = ks * 512;

    f4 acc0 = 0.f, acc1 = 0.f, acc2 = 0.f, acc3 = 0.f;
    const u16* ap  = sc + (size_t)(i0 + m) * 4096 + k0 + quad * 8;
    const u16* bp  = BT + (size_t)m * 4096 + k0 + quad * 8;   // n = m + nt*16
    #pragma unroll 4
    for (int kc = 0; kc < 512; kc += 32) {
        s8v a  = *(const s8v*)(ap + kc);
        s8v b0 = *(const s8v*)(bp + kc);
        s8v b1 = *(const s8v*)(bp + 16 * 4096 + kc);
        s8v b2 = *(const s8v*)(bp + 32 * 4096 + kc);
        s8v b3 = *(const s8v*)(bp + 48 * 4096 + kc);
        acc0 = __builtin_amdgcn_mfma_f32_16x16x32_bf16(a, b0, acc0, 0, 0, 0);
        acc1 = __builtin_amdgcn_mfma_f32_16x16x32_bf16(a, b1, acc1, 0, 0, 0);
        acc2 = __builtin_amdgcn_mfma_f32_16x16x32_bf16(a, b2, acc2, 0, 0, 0);
        acc3 = __builtin_amdgcn_mfma_f32_16x16x32_bf16(a, b3, acc3, 0, 0, 0);
    }
    float* pb = part + (size_t)ks * 262144;
    #pragma unroll
    for (int r = 0; r < 4; ++r) {
        const size_t ro = (size_t)(i0 + quad * 4 + r) * 64 + m;
        pb[ro +  0] = acc0[r];
        pb[ro + 16] = acc1[r];
        pb[ro + 32] = acc2[r];
        pb[ro + 48] = acc3[r];
    }
}

// ---------------------------------------------------------------------------
// Two-layer node update + fused 8-way K-split reduction + optional fused
// rdvc[n] = dst[n] . wvcrow (wave-reduce at write time). 1024 blocks x 256.
__global__ __launch_bounds__(256) void k_mlp2(
    const float* __restrict__ objx, const float* __restrict__ base,
    const float* __restrict__ W1, const float* __restrict__ part,
    const float* __restrict__ W2, float* __restrict__ dst,
    const float* __restrict__ wvcrow, float* __restrict__ rdvc)
{
    __shared__ float mid[4][64];
    __shared__ float accs[4][64];
    const int t = threadIdx.x, w = t >> 6, h = t & 63;
    const int n = blockIdx.x * 4 + w;
    float v = 0.f;
    #pragma unroll
    for (int j = 0; j < 8; ++j) v += part[(size_t)j * 262144 + n*64 + h];
    accs[w][h] = v;
    float m = 0.f;
    for (int k = 0; k < 64; ++k) m += objx[k] * W1[k*64 + h];
    for (int k = 0; k < 64; ++k) m += base[n*64 + k] * W1[(64+k)*64 + h];
    mid[w][h] = fmaxf(m, 0.f);
    __syncthreads();
    float o = 0.f;
    for (int k = 0; k < 64; ++k) o += mid[w][k] * W2[k*64 + h];
    for (int k = 0; k < 64; ++k) o += accs[w][k] * W2[(64+k)*64 + h];
    o = fmaxf(o, 0.f);
    dst[n*64 + h] = o;
    if (rdvc) {
        float rv = o * wvcrow[h];
        #pragma unroll
        for (int off = 32; off; off >>= 1) rv += __shfl_down(rv, off, 64);
        if (h == 0) rdvc[n] = rv;
    }
}

extern "C" void kernel_launch(void* const* d_in, const int* in_sizes, int n_in,
                              void* d_out, int out_size, void* d_ws, size_t ws_size,
                              hipStream_t stream)
{
    const float* col_hidden = (const float*)d_in[0];
    const float* row_hidden = (const float*)d_in[1];
    const float* obj_hidden = (const float*)d_in[2];
    const float* cv_supp    = (const float*)d_in[3];
    const float* vc_supp    = (const float*)d_in[4];
    const float* vo_supp    = (const float*)d_in[5];
    const float* co_supp    = (const float*)d_in[6];
    const float* W_vo       = (const float*)d_in[7];
    const float* W_oc       = (const float*)d_in[8];
    const float* W_vc       = (const float*)d_in[9];
    const float* W_co       = (const float*)d_in[10];
    const float* W_ov       = (const float*)d_in[11];
    const float* W_cv       = (const float*)d_in[12];
    const float* w_attn_vo  = (const float*)d_in[13];
    const float* b_attn_vo  = (const float*)d_in[14];
    const float* w_attn_co  = (const float*)d_in[15];
    const float* b_attn_co  = (const float*)d_in[16];
    const float* w_cv_col   = (const float*)d_in[17];
    const float* w_cv_supp  = (const float*)d_in[18];
    const float* w_cv_row   = (const float*)d_in[19];
    const float* b_cv       = (const float*)d_in[20];
    const float* w_vc_row   = (const float*)d_in[21];
    const float* w_vc_supp  = (const float*)d_in[22];
    const float* w_vc_col   = (const float*)d_in[23];
    const float* b_vc       = (const float*)d_in[24];

    float* out = (float*)d_out;
    float* ws  = (float*)d_ws;
    u16* SC  = (u16*)(ws + WS_SC);
    u16* BT1 = (u16*)(ws + WS_BT1);
    u16* BT2 = (u16*)(ws + WS_BT2);

    // 1) dots + small passthrough + v->o attn partials + col_hidden^T bf16
    k_front<<<3168, 256, 0, stream>>>(col_hidden, row_hidden, w_cv_col, w_vc_col, w_cv_row,
                                      ws + WS_CDCV, ws + WS_CDVC, ws + WS_RDCV,
                                      vo_supp, co_supp, out + OUT_VO, out + OUT_CO,
                                      obj_hidden, w_attn_vo, b_attn_vo, ws + WS_VO_P, BT1);
    // 2) pure pass-through copy of BOTH supp tensors (diagnostic copy shape)
    k_copy<<<16384, 256, 0, stream>>>(cv_supp, vc_supp, out + OUT_CV, out + OUT_VC);
    // 3) bf16 score_cv plane
    k_score<<<4096, 256, 0, stream>>>(cv_supp, cv_supp + PLANE,
                                      ws + WS_RDCV, ws + WS_CDCV, w_cv_supp, b_cv, SC);
    // 4) v_out = score_cv @ col_hidden (MFMA), + obj v->o update
    k_gemm<<<513, 256, 0, stream>>>(SC, BT1, ws + WS_GPART,
                                    obj_hidden, ws + WS_VO_P, W_vo, ws + WS_OBJ1);
    // 5) row_next = relu([relu([obj1|row_hidden]W_oc) | v_out] W_vc), + rdvc
    k_mlp2<<<1024, 256, 0, stream>>>(ws + WS_OBJ1, row_hidden, W_oc, ws + WS_GPART, W_vc,
                                     out + OUT_ROW, w_vc_row, ws + WS_RDVC);
    // 6) c->o attn partials + row_next^T bf16
    k_attn<<<80, 256, 0, stream>>>(out + OUT_ROW, co_supp, ws + WS_OBJ1, w_attn_co,
                                   b_attn_co, ws + WS_CO_P, BT2);
    // 7) bf16 score_vc plane
    k_score<<<4096, 256, 0, stream>>>(vc_supp, vc_supp + PLANE,
                                      ws + WS_CDVC, ws + WS_RDVC, w_vc_supp, b_vc, SC);
    // 8) c_out = score_vc @ row_next (MFMA), + final obj update
    k_gemm<<<513, 256, 0, stream>>>(SC, BT2, ws + WS_GPART,
                                    ws + WS_OBJ1, ws + WS_CO_P, W_co, out + OUT_OBJ);
    // 9) col_next = relu([relu([obj|col_hidden]W_ov) | c_out] W_cv)
    k_mlp2<<<1024, 256, 0, stream>>>(out + OUT_OBJ, col_hidden, W_ov, ws + WS_GPART, W_cv,
                                     out + OUT_COL, nullptr, nullptr);
}

// Round 8
// 578.459 us; speedup vs baseline: 1.1187x; 1.1187x over previous
//
#include <hip/hip_runtime.h>
#include <math.h>

typedef float f4  __attribute__((ext_vector_type(4)));
typedef short s8v __attribute__((ext_vector_type(8)));   // 8 bf16 (4 VGPRs)
typedef unsigned short u16;
typedef u16 us4 __attribute__((ext_vector_type(4)));

#define PLANE (4096*4096)

// ---- output offsets (floats), concatenated return order ----
#define OUT_COL 0
#define OUT_ROW 262144
#define OUT_OBJ 524288
#define OUT_CV  524352
#define OUT_VC  34078784
#define OUT_VO  67633216
#define OUT_CO  67641408

// ---- workspace offsets (floats) ----
#define WS_VO_P  0         // [16][64] v->o attention per-block partials
#define WS_CO_P  1024      // [16][64] c->o attention per-block partials
#define WS_OBJ1  2048      // [64]  obj after v->o update
#define WS_RDCV  2112      // [4096] row_hidden . w_cv_row
#define WS_CDCV  6208      // [4096] col_hidden . w_cv_col
#define WS_RDVC  10304     // [4096] row_next . w_vc_row
#define WS_CDVC  14400     // [4096] col_hidden . w_vc_col
#define WS_GPART 18496     // [16][4096*64] f32 K-split partials (16 MB)
#define WS_BT1   4212800   // [64][4096] bf16 col_hidden^T
#define WS_BT2   4343872   // [64][4096] bf16 row_next^T

__device__ __forceinline__ float sigf(float x) {
    return 1.0f / (1.0f + __expf(-x));
}
__device__ __forceinline__ u16 f2bf(float x) {       // RNE float->bf16
    unsigned u = __float_as_uint(x);
    return (u16)((u + 0x7FFFu + ((u >> 16) & 1u)) >> 16);
}

// ---------------------------------------------------------------------------
// 64x64 fp32 -> bf16 transpose tile: BT[h][k0+c] = X[k0+c][h].
__device__ __forceinline__ void transpose_tile(int k0, int t,
    const float* __restrict__ X, u16* __restrict__ BT, float* lds /*64*72*/)
{
    #pragma unroll
    for (int it = 0; it < 4; ++it) {
        const int idx = it * 256 + t;          // 0..1023 f4 units
        const int r = idx >> 4, c4 = (idx & 15) * 4;
        f4 v = *(const f4*)(X + (size_t)(k0 + r) * 64 + c4);
        *(f4*)(lds + r * 72 + c4) = v;
    }
    __syncthreads();
    #pragma unroll
    for (int it = 0; it < 4; ++it) {
        const int idx = it * 256 + t;          // 0..1023
        const int h = idx >> 4, q = (idx & 15) * 4;
        us4 o;
        o.x = f2bf(lds[(q + 0) * 72 + h]);
        o.y = f2bf(lds[(q + 1) * 72 + h]);
        o.z = f2bf(lds[(q + 2) * 72 + h]);
        o.w = f2bf(lds[(q + 3) * 72 + h]);
        *(us4*)(BT + (size_t)h * 4096 + k0 + q) = o;
    }
}

// ---------------------------------------------------------------------------
// Attention body: per-block partial, no global atomics.
__device__ __forceinline__ void attn_body(
    int blk, int t, const float* __restrict__ X, const float* __restrict__ supp,
    const float* __restrict__ obj, const float* __restrict__ wat,
    const float* __restrict__ bat, float* __restrict__ accP,
    float* sA, float* sAcc)
{
    const int i = blk * 256 + t;
    float od = 0.f;
    for (int h = 0; h < 64; ++h) od += obj[h] * wat[66 + h];
    float x = bat[0] + od + supp[i*2] * wat[64] + supp[i*2+1] * wat[65];
    const f4* Xr = (const f4*)(X + i*64);
    f4 xd = 0.f;
    #pragma unroll
    for (int q = 0; q < 16; ++q) xd += Xr[q] * ((const f4*)wat)[q];
    x += xd.x + xd.y + xd.z + xd.w;
    sA[t] = sigf(x);
    if (t < 64) sAcc[t] = 0.f;
    __syncthreads();
    const int w = t >> 6, h = t & 63;
    const int base = blk * 256 + w * 64;
    float partial = 0.f;
    for (int j = 0; j < 64; ++j)
        partial += sA[w*64 + j] * X[(base + j)*64 + h];
    atomicAdd(&sAcc[h], partial);
    __syncthreads();
    if (t < 64) accP[blk*64 + t] = sAcc[t];
}

// ---------------------------------------------------------------------------
// Front: 3072 dot blocks + 16 small-copy + 16 v->o attn + 64 BT1-transpose.
__global__ __launch_bounds__(256) void k_front(
    const float* __restrict__ col_hidden, const float* __restrict__ row_hidden,
    const float* __restrict__ w_cv_col, const float* __restrict__ w_vc_col,
    const float* __restrict__ w_cv_row,
    float* __restrict__ cdcv, float* __restrict__ cdvc, float* __restrict__ rdcv,
    const float* __restrict__ vo_supp, const float* __restrict__ co_supp,
    float* __restrict__ out_vo, float* __restrict__ out_co,
    const float* __restrict__ obj_hidden, const float* __restrict__ w_attn_vo,
    const float* __restrict__ b_attn_vo, float* __restrict__ voP,
    u16* __restrict__ BT1)
{
    __shared__ float sA[256];
    __shared__ float sAcc[64];
    __shared__ float tr[64*72];
    const int t = threadIdx.x;
    if (blockIdx.x < 3072) {
        const int gw = blockIdx.x * 4 + (t >> 6);
        const int lane = t & 63;
        const int which = gw >> 12;
        const int row = gw & 4095;
        const float* x; const float* w; float* dst;
        if (which == 0)      { x = col_hidden; w = w_cv_col; dst = cdcv; }
        else if (which == 1) { x = col_hidden; w = w_vc_col; dst = cdvc; }
        else                 { x = row_hidden; w = w_cv_row; dst = rdcv; }
        float v = x[row * 64 + lane] * w[lane];
        #pragma unroll
        for (int off = 32; off; off >>= 1) v += __shfl_down(v, off, 64);
        if (lane == 0) dst[row] = v;
        return;
    }
    if (blockIdx.x < 3088) {
        const int idx = (blockIdx.x - 3072) * 256 + t;
        if (idx < 2048) ((f4*)out_vo)[idx] = ((const f4*)vo_supp)[idx];
        else            ((f4*)out_co)[idx - 2048] = ((const f4*)co_supp)[idx - 2048];
        return;
    }
    if (blockIdx.x < 3104) {
        attn_body(blockIdx.x - 3088, t, col_hidden, vo_supp, obj_hidden,
                  w_attn_vo, b_attn_vo, voP, sA, sAcc);
        return;
    }
    transpose_tile((blockIdx.x - 3104) * 64, t, col_hidden, BT1, tr);
}

// ---------------------------------------------------------------------------
// c->o attention (16 blocks) + BT2 transpose of row_next (64 blocks).
__global__ __launch_bounds__(256) void k_attn(
    const float* __restrict__ X, const float* __restrict__ supp,
    const float* __restrict__ obj, const float* __restrict__ wat,
    const float* __restrict__ bat, float* __restrict__ accP,
    u16* __restrict__ BT2)
{
    __shared__ float sA[256];
    __shared__ float sAcc[64];
    __shared__ float tr[64*72];
    if (blockIdx.x < 16) {
        attn_body(blockIdx.x, threadIdx.x, X, supp, obj, wat, bat, accP, sA, sAcc);
        return;
    }
    transpose_tile((blockIdx.x - 16) * 64, threadIdx.x, X, BT2, tr);
}

// ---------------------------------------------------------------------------
// FULLY FUSED streaming GEMM: one pass over one supp tensor does
//   (a) pass-through copy to output,
//   (b) masked sigmoid score (in registers, bf16),
//   (c) MFMA against BT (L2-resident 0.5 MB) into K-split partials.
// No LDS, no barriers in the K-loop. A-operand pattern = 16 rows x 64B
// granules per wave (full line coverage via 4 quads); pass-through writes
// land on identical addresses. grid = 64 mblk x 16 ks (+1 obj tail block);
// ks is the fast index -> consecutive blocks sweep a contiguous 1 MB band.
__global__ __launch_bounds__(256, 4) void k_fgemm(
    const float* __restrict__ supp0, const float* __restrict__ supp1,
    const u16* __restrict__ BT,
    const float* __restrict__ rdot, const float* __restrict__ cdot,
    const float* __restrict__ wsup, const float* __restrict__ bias,
    float* __restrict__ pass0, float* __restrict__ pass1,
    float* __restrict__ part,
    const float* __restrict__ objL, const float* __restrict__ objRp,
    const float* __restrict__ Wobj, float* __restrict__ objDst)
{
    __shared__ float rsum[64];
    const int t = threadIdx.x;
    if (blockIdx.x == 1024) {        // obj update tail block
        if (t < 64) {
            float r = 0.f;
            for (int b = 0; b < 16; ++b) r += objRp[b*64 + t];
            rsum[t] = r;
        }
        __syncthreads();
        if (t < 64) {
            float acc = 0.f;
            for (int k = 0; k < 64; ++k) acc += objL[k] * Wobj[k*64 + t];
            for (int k = 0; k < 64; ++k) acc += rsum[k] * Wobj[(64+k)*64 + t];
            objDst[t] = fmaxf(acc, 0.f);
        }
        return;
    }
    const int mblk = blockIdx.x >> 4;     // slow: 0..63
    const int ks   = blockIdx.x & 15;     // fast: 0..15
    const int wv   = t >> 6, lane = t & 63;
    const int i0   = mblk * 64 + wv * 16;
    const int m    = lane & 15, quad = lane >> 4;
    const int k0   = ks * 256;
    const float rd = rdot[i0 + m];
    const float w0 = wsup[0], w1 = wsup[1], bv = bias[0];

    f4 acc0 = 0.f, acc1 = 0.f, acc2 = 0.f, acc3 = 0.f;
    const size_t arow = (size_t)(i0 + m) * 4096 + k0 + quad * 8;
    const u16* bp = BT + (size_t)m * 4096 + k0 + quad * 8;   // n = m + 16*nt

    for (int kc = 0; kc < 256; kc += 32) {
        // A: 8 k-elements from each plane (2x16B per plane)
        f4 a0l = *(const f4*)(supp0 + arow + kc);
        f4 a0h = *(const f4*)(supp0 + arow + kc + 4);
        f4 a1l = *(const f4*)(supp1 + arow + kc);
        f4 a1h = *(const f4*)(supp1 + arow + kc + 4);
        // pass-through copy (same addresses)
        *(f4*)(pass0 + arow + kc)     = a0l;
        *(f4*)(pass0 + arow + kc + 4) = a0h;
        *(f4*)(pass1 + arow + kc)     = a1l;
        *(f4*)(pass1 + arow + kc + 4) = a1h;
        // masked sigmoid scores -> bf16 A-fragment
        const int kabs = k0 + quad * 8 + kc;
        f4 cdl = *(const f4*)(cdot + kabs);
        f4 cdh = *(const f4*)(cdot + kabs + 4);
        f4 lgl = rd + cdl + w0 * a0l + w1 * a1l + bv;
        f4 lgh = rd + cdh + w0 * a0h + w1 * a1h + bv;
        s8v a;
        a[0] = (short)((a0l.x != 0.f) ? f2bf(sigf(lgl.x)) : (u16)0);
        a[1] = (short)((a0l.y != 0.f) ? f2bf(sigf(lgl.y)) : (u16)0);
        a[2] = (short)((a0l.z != 0.f) ? f2bf(sigf(lgl.z)) : (u16)0);
        a[3] = (short)((a0l.w != 0.f) ? f2bf(sigf(lgl.w)) : (u16)0);
        a[4] = (short)((a0h.x != 0.f) ? f2bf(sigf(lgh.x)) : (u16)0);
        a[5] = (short)((a0h.y != 0.f) ? f2bf(sigf(lgh.y)) : (u16)0);
        a[6] = (short)((a0h.z != 0.f) ? f2bf(sigf(lgh.z)) : (u16)0);
        a[7] = (short)((a0h.w != 0.f) ? f2bf(sigf(lgh.w)) : (u16)0);
        // B fragments (L2-hot) + MFMA
        s8v b0 = *(const s8v*)(bp + kc);
        s8v b1 = *(const s8v*)(bp + 16 * 4096 + kc);
        s8v b2 = *(const s8v*)(bp + 32 * 4096 + kc);
        s8v b3 = *(const s8v*)(bp + 48 * 4096 + kc);
        acc0 = __builtin_amdgcn_mfma_f32_16x16x32_bf16(a, b0, acc0, 0, 0, 0);
        acc1 = __builtin_amdgcn_mfma_f32_16x16x32_bf16(a, b1, acc1, 0, 0, 0);
        acc2 = __builtin_amdgcn_mfma_f32_16x16x32_bf16(a, b2, acc2, 0, 0, 0);
        acc3 = __builtin_amdgcn_mfma_f32_16x16x32_bf16(a, b3, acc3, 0, 0, 0);
    }
    float* pb = part + (size_t)ks * 262144;
    #pragma unroll
    for (int r = 0; r < 4; ++r) {
        const size_t ro = (size_t)(i0 + quad * 4 + r) * 64 + m;
        pb[ro +  0] = acc0[r];
        pb[ro + 16] = acc1[r];
        pb[ro + 32] = acc2[r];
        pb[ro + 48] = acc3[r];
    }
}

// ---------------------------------------------------------------------------
// Two-layer node update + fused 16-way K-split reduction + optional fused
// rdvc[n] = dst[n] . wvcrow (wave-reduce at write time). 1024 blocks x 256.
__global__ __launch_bounds__(256) void k_mlp2(
    const float* __restrict__ objx, const float* __restrict__ base,
    const float* __restrict__ W1, const float* __restrict__ part,
    const float* __restrict__ W2, float* __restrict__ dst,
    const float* __restrict__ wvcrow, float* __restrict__ rdvc)
{
    __shared__ float mid[4][64];
    __shared__ float accs[4][64];
    const int t = threadIdx.x, w = t >> 6, h = t & 63;
    const int n = blockIdx.x * 4 + w;
    float v = 0.f;
    #pragma unroll
    for (int j = 0; j < 16; ++j) v += part[(size_t)j * 262144 + n*64 + h];
    accs[w][h] = v;
    float m = 0.f;
    for (int k = 0; k < 64; ++k) m += objx[k] * W1[k*64 + h];
    for (int k = 0; k < 64; ++k) m += base[n*64 + k] * W1[(64+k)*64 + h];
    mid[w][h] = fmaxf(m, 0.f);
    __syncthreads();
    float o = 0.f;
    for (int k = 0; k < 64; ++k) o += mid[w][k] * W2[k*64 + h];
    for (int k = 0; k < 64; ++k) o += accs[w][k] * W2[(64+k)*64 + h];
    o = fmaxf(o, 0.f);
    dst[n*64 + h] = o;
    if (rdvc) {
        float rv = o * wvcrow[h];
        #pragma unroll
        for (int off = 32; off; off >>= 1) rv += __shfl_down(rv, off, 64);
        if (h == 0) rdvc[n] = rv;
    }
}

extern "C" void kernel_launch(void* const* d_in, const int* in_sizes, int n_in,
                              void* d_out, int out_size, void* d_ws, size_t ws_size,
                              hipStream_t stream)
{
    const float* col_hidden = (const float*)d_in[0];
    const float* row_hidden = (const float*)d_in[1];
    const float* obj_hidden = (const float*)d_in[2];
    const float* cv_supp    = (const float*)d_in[3];
    const float* vc_supp    = (const float*)d_in[4];
    const float* vo_supp    = (const float*)d_in[5];
    const float* co_supp    = (const float*)d_in[6];
    const float* W_vo       = (const float*)d_in[7];
    const float* W_oc       = (const float*)d_in[8];
    const float* W_vc       = (const float*)d_in[9];
    const float* W_co       = (const float*)d_in[10];
    const float* W_ov       = (const float*)d_in[11];
    const float* W_cv       = (const float*)d_in[12];
    const float* w_attn_vo  = (const float*)d_in[13];
    const float* b_attn_vo  = (const float*)d_in[14];
    const float* w_attn_co  = (const float*)d_in[15];
    const float* b_attn_co  = (const float*)d_in[16];
    const float* w_cv_col   = (const float*)d_in[17];
    const float* w_cv_supp  = (const float*)d_in[18];
    const float* w_cv_row   = (const float*)d_in[19];
    const float* b_cv       = (const float*)d_in[20];
    const float* w_vc_row   = (const float*)d_in[21];
    const float* w_vc_supp  = (const float*)d_in[22];
    const float* w_vc_col   = (const float*)d_in[23];
    const float* b_vc       = (const float*)d_in[24];

    float* out = (float*)d_out;
    float* ws  = (float*)d_ws;
    u16* BT1 = (u16*)(ws + WS_BT1);
    u16* BT2 = (u16*)(ws + WS_BT2);

    // 1) dots + small passthrough + v->o attn partials + col_hidden^T bf16
    k_front<<<3168, 256, 0, stream>>>(col_hidden, row_hidden, w_cv_col, w_vc_col, w_cv_row,
                                      ws + WS_CDCV, ws + WS_CDVC, ws + WS_RDCV,
                                      vo_supp, co_supp, out + OUT_VO, out + OUT_CO,
                                      obj_hidden, w_attn_vo, b_attn_vo, ws + WS_VO_P, BT1);
    // 2) fused: cv passthrough + score_cv + v_out partials (+ obj v->o update)
    k_fgemm<<<1025, 256, 0, stream>>>(cv_supp, cv_supp + PLANE, BT1,
                                      ws + WS_RDCV, ws + WS_CDCV, w_cv_supp, b_cv,
                                      out + OUT_CV, out + OUT_CV + PLANE, ws + WS_GPART,
                                      obj_hidden, ws + WS_VO_P, W_vo, ws + WS_OBJ1);
    // 3) row_next = relu([relu([obj1|row_hidden]W_oc) | v_out] W_vc), + rdvc
    k_mlp2<<<1024, 256, 0, stream>>>(ws + WS_OBJ1, row_hidden, W_oc, ws + WS_GPART, W_vc,
                                     out + OUT_ROW, w_vc_row, ws + WS_RDVC);
    // 4) c->o attn partials + row_next^T bf16
    k_attn<<<80, 256, 0, stream>>>(out + OUT_ROW, co_supp, ws + WS_OBJ1, w_attn_co,
                                   b_attn_co, ws + WS_CO_P, BT2);
    // 5) fused: vc passthrough + score_vc + c_out partials (+ final obj update)
    k_fgemm<<<1025, 256, 0, stream>>>(vc_supp, vc_supp + PLANE, BT2,
                                      ws + WS_CDVC, ws + WS_RDVC, w_vc_supp, b_vc,
                                      out + OUT_VC, out + OUT_VC + PLANE, ws + WS_GPART,
                                      ws + WS_OBJ1, ws + WS_CO_P, W_co, out + OUT_OBJ);
    // 6) col_next = relu([relu([obj|col_hidden]W_ov) | c_out] W_cv)
    k_mlp2<<<1024, 256, 0, stream>>>(out + OUT_OBJ, col_hidden, W_ov, ws + WS_GPART, W_cv,
                                     out + OUT_COL, nullptr, nullptr);
}